// Round 9
// baseline (274.374 us; speedup 1.0000x reference)
//
#include <hip/hip_runtime.h>
#include <stdint.h>

// PAM module: B=4, C=512, N=4096, C8=64.
// R14: VALUBusy (38%) is k_fused's top pipe; QK+exp were computed 2x
// (per c-half) and v went through LDS. New k_fused: c-full 512 blocks
// (n-tile 64, 256 blocks, 1024 thr/16 waves) -> QK MFMAs + exp HALVE
// chip-wide; v8 read global->VGPR (L2-resident, XCD-clustered per batch,
// loads issued before QK so QK+exp hides latency) -> v LDS traffic and
// A-side swizzle VALU deleted. P layout / PV math bit-identical to R13.

typedef unsigned short u16;
typedef unsigned char u8;
typedef __attribute__((ext_vector_type(8))) short short8;  // 8 x bf16
typedef __attribute__((ext_vector_type(4))) float f32x4;
typedef __attribute__((ext_vector_type(16))) float f32x16;
typedef __attribute__((ext_vector_type(4))) int i32x4;
typedef __attribute__((ext_vector_type(8))) int i32x8;

#define ASYNC16(gp, lp)                                                        \
  __builtin_amdgcn_global_load_lds(                                            \
      (__attribute__((address_space(1))) void*)(void*)(gp),                    \
      (__attribute__((address_space(3))) void*)(lp), 16, 0, 0)

#define WAIT_VM0 0x0F70    // vmcnt==0, ignore exp/lgkm
#define WAIT_VM1 0x0F71    // vmcnt<=1
#define WAIT_LGKM0 0xC07F  // lgkmcnt==0

#define EXP_SHIFT 5.0f
#define EXP_CAP 57000.0f  // just under bf8 e5m2 max (57344)

__device__ __forceinline__ u16 f2bf(float f) {  // RNE float->bf16
  uint32_t u = __float_as_uint(f);
  u += 0x7FFFu + ((u >> 16) & 1u);
  return (u16)(u >> 16);
}

__device__ __forceinline__ u8 f2fp8(float f) {  // clamped e4m3
  f = fminf(fmaxf(f, -440.f), 440.f);
  int r = __builtin_amdgcn_cvt_pk_fp8_f32(f, f, 0, false);
  return (u8)(r & 0xFF);
}

// ---------------- transpose + cast: x (B,C,N) f32 -> xT (B,N,C) bf16 --------
__global__ __launch_bounds__(256) void k_transpose(const float* __restrict__ x,
                                                   u16* __restrict__ xT) {
  __shared__ float tile[32][33];
  const int b = blockIdx.z;
  const int nb = blockIdx.x * 32;
  const int cb = blockIdx.y * 32;
  const int t = threadIdx.x;
  {
    const int nl = t & 31, c0 = t >> 5;
    const float* xp = x + ((size_t)b * 512 + cb) * 4096 + nb;
#pragma unroll
    for (int i = 0; i < 4; ++i) {
      const int cl = c0 + i * 8;
      tile[cl][nl] = xp[(size_t)cl * 4096 + nl];
    }
  }
  __syncthreads();
  {
    const int cl = t & 31, n0 = t >> 5;
    u16* xtp = xT + ((size_t)b * 4096 + nb) * 512 + cb;
#pragma unroll
    for (int i = 0; i < 4; ++i) {
      const int nl = n0 + i * 8;
      xtp[(size_t)nl * 512 + cl] = f2bf(tile[cl][nl]);
    }
  }
}

// weights -> bf16. wqk = concat(Wq,Wk) (128x512), wv (512x512)
__global__ __launch_bounds__(256) void k_wcast(const float* __restrict__ Wq,
                                               const float* __restrict__ Wk,
                                               const float* __restrict__ Wv,
                                               u16* __restrict__ wqk,
                                               u16* __restrict__ wv) {
  const int idx = blockIdx.x * 256 + threadIdx.x;
  if (idx < 128 * 512) {
    const int r = idx >> 9, c = idx & 511;
    const float f = (r < 64) ? Wq[r * 512 + c] : Wk[(r - 64) * 512 + c];
    wqk[idx] = f2bf(f);
  } else {
    const int j = idx - 128 * 512;
    if (j < 512 * 512) wv[j] = f2bf(Wv[j]);
  }
}

// ------------- bf16 gemm_bt core: 128x128 tile, BK=64, swizzled LDS ---------
__device__ __forceinline__ void gemm_bt_tile(const u16* __restrict__ A,
                                             const u16* __restrict__ B,
                                             const int K, const int rowA0,
                                             const int colB0, u16* smem,
                                             f32x4 acc[4][4]) {
  const int t = threadIdx.x;
  const int lane = t & 63, wave = t >> 6;
  const int quad = lane >> 4, l15 = lane & 15;
  const int wr = wave >> 1, wc = wave & 1;
  u16* As = smem;          // [128][64] swizzled
  u16* Bs = smem + 8192;
  const f32x4 zero = {0.f, 0.f, 0.f, 0.f};
#pragma unroll
  for (int i = 0; i < 4; ++i)
#pragma unroll
    for (int j = 0; j < 4; ++j) acc[i][j] = zero;

  const int srow = t >> 3;                        // 0..31
  const int c8 = (lane & 7) ^ (lane >> 3);        // swizzled 16B chunk
  const u16* ga = A + (size_t)(rowA0 + srow) * K + c8 * 8;
  const u16* gb = B + (size_t)(colB0 + srow) * K + c8 * 8;
  char* la = (char*)As + wave * 1024;
  char* lb = (char*)Bs + wave * 1024;
  const size_t rK32 = (size_t)32 * K;

  const int sw0 = (quad) ^ (l15 & 7);
  const int sw1 = (4 + quad) ^ (l15 & 7);

  for (int k0 = 0; k0 < K; k0 += 64) {
    ASYNC16(ga + k0, la);
    ASYNC16(ga + k0 + rK32, la + 4096);
    ASYNC16(ga + k0 + 2 * rK32, la + 8192);
    ASYNC16(ga + k0 + 3 * rK32, la + 12288);
    ASYNC16(gb + k0, lb);
    ASYNC16(gb + k0 + rK32, lb + 4096);
    ASYNC16(gb + k0 + 2 * rK32, lb + 8192);
    ASYNC16(gb + k0 + 3 * rK32, lb + 12288);
    __syncthreads();
#pragma unroll
    for (int s = 0; s < 2; ++s) {
      const int sw = s ? sw1 : sw0;
      short8 a[4], b[4];
#pragma unroll
      for (int i = 0; i < 4; ++i)
        a[i] = *(const short8*)(As + (wr * 64 + i * 16 + l15) * 64 + sw * 8);
#pragma unroll
      for (int j = 0; j < 4; ++j)
        b[j] = *(const short8*)(Bs + (wc * 64 + j * 16 + l15) * 64 + sw * 8);
#pragma unroll
      for (int i = 0; i < 4; ++i)
#pragma unroll
        for (int j = 0; j < 4; ++j)
          acc[i][j] = __builtin_amdgcn_mfma_f32_16x16x32_bf16(a[i], b[j],
                                                              acc[i][j], 0, 0, 0);
    }
    __syncthreads();
  }
}

// ---- merged projections: by<4 -> v tile; by==4 -> qk tile ------------------
__global__ __launch_bounds__(256) void k_proj(const u16* __restrict__ xT,
                                              const u16* __restrict__ wqk,
                                              const u16* __restrict__ wv,
                                              const float* __restrict__ bq,
                                              const float* __restrict__ bk,
                                              const float* __restrict__ bv,
                                              u16* __restrict__ q,
                                              u16* __restrict__ kT,
                                              u8* __restrict__ v8) {
  __shared__ u16 smem[16384];
  const int b = blockIdx.z;
  const int by = blockIdx.y;
  const int t = threadIdx.x, lane = t & 63, wave = t >> 6;
  const int quad = lane >> 4, l15 = lane & 15;
  const int wr = wave >> 1, wc = wave & 1;
  f32x4 acc[4][4];

  if (by == 4) {  // q/k projection: C[n][o2] = xT @ wqk^T
    const int rowA0 = blockIdx.x * 128;
    gemm_bt_tile(xT + (size_t)b * 4096 * 512, wqk, 512, rowA0, 0, smem, acc);
#pragma unroll
    for (int j = 0; j < 4; ++j) {
      const int col = wc * 64 + j * 16 + l15;
      const float bias = (col < 64) ? bq[col] : bk[col - 64];
#pragma unroll
      for (int i = 0; i < 4; ++i) {
#pragma unroll
        for (int r = 0; r < 4; ++r) {
          const int row = rowA0 + wr * 64 + i * 16 + quad * 4 + r;
          const float val = acc[i][j][r] + bias;
          if (col < 64)
            q[((size_t)b * 4096 + row) * 64 + col] = f2bf(val);
          else
            kT[((size_t)b * 4096 + row) * 64 + (col - 64)] = f2bf(val);
        }
      }
    }
  } else {  // v projection: v8[c][n] = e4m3(Wv @ x + bv)
    const int rowA0 = by * 128;
    const int colB0 = blockIdx.x * 128;
    gemm_bt_tile(wv, xT + (size_t)b * 4096 * 512, 512, rowA0, colB0, smem, acc);
#pragma unroll
    for (int i = 0; i < 4; ++i) {
#pragma unroll
      for (int r = 0; r < 4; ++r) {
        const int row = rowA0 + wr * 64 + i * 16 + quad * 4 + r;
        const float bias = bv[row];
#pragma unroll
        for (int j = 0; j < 4; ++j) {
          const int col = colB0 + wc * 64 + j * 16 + l15;
          v8[((size_t)b * 512 + row) * 4096 + col] = f2fp8(acc[i][j][r] + bias);
        }
      }
    }
  }
}

// ---------------- fused attention+PV (c-full, v direct-global) ---------------
// Per block: n-tile 64, c-full 512, one batch. 1024 thr / 16 waves.
// m-loop 32 x 128. QK: wave (ms=w>>1: m-strip 16, nh=w&1: n-half 32):
// 2 k ds_reads + 4 MFMAs vs 4 register q frags. exp: 8/wave -> P_lds.
// PV: wave (wrp=w>>1: 64 c, wcp=w&1: 32 n): v from GLOBAL (8 dwordx4,
// issued before QK to hide L2 latency), 4 mfma_scale. XCD-clustered:
// 2 XCDs per batch so the 2 MB v-panel + 512 KB kT stay L2-resident.
__global__ __launch_bounds__(1024, 4) void k_fused(
    const u16* __restrict__ q, const u16* __restrict__ kT,
    const u8* __restrict__ v8, const float* __restrict__ x,
    const float* __restrict__ gamma, float* __restrict__ out) {
  __shared__ u16 k_lds[2][128 * 64];  // 32 KB, row-XOR swizzle
  __shared__ u8 P_lds[2][64 * 64];    // 8 KB [ks][64 n][64 B] bf8; q at init
  __shared__ float lsum_lds[8][64];   // 2 KB per-m-strip partials

  const int t = threadIdx.x;
  const int l = t & 63, w = t >> 6;  // 16 waves
  const int quad = l >> 4, l15 = l & 15;
  const int l31 = l & 31, h = l >> 5;

  const int bid = blockIdx.x;  // 256 blocks: 8 XCD-groups x 32
  const int xcd = bid & 7;
  const int slot = bid >> 3;            // 0..31
  const int b = xcd >> 1;               // 2 XCDs per batch
  const int n_idx = (xcd & 1) * 32 + slot;
  const int n0 = n_idx * 64;

  const u16* qg = q + ((size_t)b * 4096 + n0) * 64;
  const u16* kg = kT + (size_t)b * 4096 * 64;
  const u8* vg = v8 + (size_t)b * 512 * 4096;

  // staging source addrs (LDS dst = wave-uniform base + lane*16)
  const int kr = t >> 3, kc = t & 7;  // k: 1024 chunks, 128B rows
  const u16* ksg = kg + kr * 64 + (kc ^ (kr & 7)) * 8;  // + m0*64
  // q: 512 chunks (waves 0-7), 64 rows
  const u16* qsg = qg + kr * 64 + (kc ^ (kr & 7)) * 8;

  // ---- prologue: k tile 0 (all waves) + q (waves 0-7) ----
  ASYNC16(ksg, (char*)k_lds[0] + w * 1024);
  if (w < 8) ASYNC16(qsg, (char*)P_lds[0] + w * 1024);
  __builtin_amdgcn_s_waitcnt(WAIT_VM0);
  __builtin_amdgcn_s_barrier();
  asm volatile("" ::: "memory");

  const int ms = w >> 1, nh = w & 1;  // QK decomposition
  const int sw0 = quad ^ (l15 & 7);
  const int sw1 = (4 + quad) ^ (l15 & 7);
  short8 af[2][2];  // loop-invariant q frags (strip s, sweep e)
#pragma unroll
  for (int s = 0; s < 2; ++s) {
    const u16* qrow = (const u16*)P_lds[0] + (nh * 32 + s * 16 + l15) * 64;
    af[s][0] = *(const short8*)(qrow + sw0 * 8);
    af[s][1] = *(const short8*)(qrow + sw1 * 8);
  }
  asm volatile("" ::: "memory");
  __builtin_amdgcn_s_waitcnt(WAIT_LGKM0);
  __builtin_amdgcn_s_barrier();  // q reads done -> P_lds writable
  asm volatile("" ::: "memory");

  // PV decomposition: wave (wrp: 64 c, wcp: 32 n)
  const int wrp = w >> 1, wcp = w & 1;
  const int rowB = wcp * 32 + l31;
  const int fbB = (rowB >> 1) & 3;
  const int sB1 = (2 * h) ^ fbB;
  const int sB2 = (2 * h + 1) ^ fbB;
  // v global per-lane bases: row c = wrp*64 + i*32 + l31, k-byte off h*32
  const u8* vp[2];
#pragma unroll
  for (int i = 0; i < 2; ++i)
    vp[i] = vg + (size_t)(wrp * 64 + i * 32 + l31) * 4096 + h * 32;

  // P write base: ks = ms>>2, n-row nh*32 + s*16 + l15, m-chunk (ms&3)^fbW
  const int fbW = (l15 >> 1) & 3;
  u8* Pwbase = P_lds[ms >> 2] + (nh * 32 + l15) * 64 +
               (((ms & 3) ^ fbW) * 16) + quad * 4;

  const int krow_off = (ms * 16 + l15) * 64;  // k read row offset (u16)

  f32x16 acc[2];
#pragma unroll
  for (int i = 0; i < 2; ++i)
#pragma unroll
    for (int r = 0; r < 16; ++r) acc[i][r] = 0.f;

  float lsums[2] = {0.f, 0.f};
  const f32x4 zero = {0.f, 0.f, 0.f, 0.f};

  for (int it = 0; it < 32; ++it) {
    // 1-2: k(it) staged (issued ~1 iter ago); sync (also P recycle safety)
    __builtin_amdgcn_s_waitcnt(WAIT_VM0);
    asm volatile("" ::: "memory");
    __builtin_amdgcn_s_barrier();
    asm volatile("" ::: "memory");
    const int cur = it & 1;

    // 3: issue v loads for THIS tile (latency hidden under QK+exp)
    i32x4 vA[2][2][2];  // [i][ks][half]
#pragma unroll
    for (int i = 0; i < 2; ++i)
#pragma unroll
      for (int ks = 0; ks < 2; ++ks)
#pragma unroll
        for (int hf = 0; hf < 2; ++hf)
          vA[i][ks][hf] = *(const i32x4*)(vp[i] + it * 128 + ks * 64 + hf * 16);

    // 4: stage next k tile
    if (it + 1 < 32)
      ASYNC16(ksg + (size_t)(it + 1) * 128 * 64,
              (char*)k_lds[cur ^ 1] + w * 1024);

    // 5: QK — k read once, q from regs
    const u16* kb = k_lds[cur];
    const short8 kf0 = *(const short8*)(kb + krow_off + sw0 * 8);
    const short8 kf1 = *(const short8*)(kb + krow_off + sw1 * 8);
    f32x4 eacc[2];
#pragma unroll
    for (int s = 0; s < 2; ++s) eacc[s] = zero;
    __builtin_amdgcn_s_setprio(1);
#pragma unroll
    for (int s = 0; s < 2; ++s)
      eacc[s] = __builtin_amdgcn_mfma_f32_16x16x32_bf16(kf0, af[s][0],
                                                        eacc[s], 0, 0, 0);
#pragma unroll
    for (int s = 0; s < 2; ++s)
      eacc[s] = __builtin_amdgcn_mfma_f32_16x16x32_bf16(kf1, af[s][1],
                                                        eacc[s], 0, 0, 0);
    __builtin_amdgcn_s_setprio(0);

    // 6: exp -> bf8 -> P_lds
#pragma unroll
    for (int s = 0; s < 2; ++s) {
      const float e0 = fminf(__expf(eacc[s][0] - EXP_SHIFT), EXP_CAP);
      const float e1 = fminf(__expf(eacc[s][1] - EXP_SHIFT), EXP_CAP);
      const float e2 = fminf(__expf(eacc[s][2] - EXP_SHIFT), EXP_CAP);
      const float e3 = fminf(__expf(eacc[s][3] - EXP_SHIFT), EXP_CAP);
      lsums[s] += (e0 + e1) + (e2 + e3);
      int pk = __builtin_amdgcn_cvt_pk_bf8_f32(e0, e1, 0, false);
      pk = __builtin_amdgcn_cvt_pk_bf8_f32(e2, e3, pk, true);
      *(int*)(Pwbase + s * 1024) = pk;  // strip step: 16 rows * 64 B
    }
    asm volatile("" ::: "memory");
    __builtin_amdgcn_s_waitcnt(WAIT_LGKM0);
    __builtin_amdgcn_s_barrier();  // 7: P(it) complete
    asm volatile("" ::: "memory");

    // 8: v loads retired (k(it+1) may stay in flight)
    if (it < 31)
      __builtin_amdgcn_s_waitcnt(WAIT_VM1);
    else
      __builtin_amdgcn_s_waitcnt(WAIT_VM0);

    // 9: PV — acc += v(e4m3) @ P^T(bf8), 2 k-steps of 64
#pragma unroll
    for (int ks = 0; ks < 2; ++ks) {
      const u8* Pb = P_lds[ks];
      i32x8 bb;
      {
        const u8* pb = Pb + rowB * 64;
        const i32x4 blo = *(const i32x4*)(pb + sB1 * 16);
        const i32x4 bhi = *(const i32x4*)(pb + sB2 * 16);
        bb = __builtin_shufflevector(blo, bhi, 0, 1, 2, 3, 4, 5, 6, 7);
      }
      __builtin_amdgcn_s_setprio(1);
#pragma unroll
      for (int i = 0; i < 2; ++i) {
        const i32x8 a = __builtin_shufflevector(vA[i][ks][0], vA[i][ks][1],
                                                0, 1, 2, 3, 4, 5, 6, 7);
        acc[i] = __builtin_amdgcn_mfma_scale_f32_32x32x64_f8f6f4(
            a, bb, acc[i], 0 /*A=e4m3*/, 1 /*B=bf8*/, 0, 0x7F, 0, 0x7F);
      }
      __builtin_amdgcn_s_setprio(0);
    }
    asm volatile("" ::: "memory");
  }

  // ---- lsum reduce: quad-sum per (strip, l15), store per m-strip ----
#pragma unroll
  for (int s = 0; s < 2; ++s) {
    lsums[s] += __shfl_xor(lsums[s], 16);
    lsums[s] += __shfl_xor(lsums[s], 32);
  }
  if (l < 16) {
#pragma unroll
    for (int s = 0; s < 2; ++s)
      lsum_lds[ms][nh * 32 + s * 16 + l] = lsums[s];
  }
  asm volatile("" ::: "memory");
  __builtin_amdgcn_s_waitcnt(WAIT_LGKM0);
  __builtin_amdgcn_s_barrier();
  asm volatile("" ::: "memory");

  // ---- epilogue: out = gamma/lsum[n] * acc + x ----
  const float g = gamma[0];
  const int col = n0 + wcp * 32 + l31;
  const int nc = wcp * 32 + l31;
  float den = 0.f;
#pragma unroll
  for (int m = 0; m < 8; ++m) den += lsum_lds[m][nc];
  const float gil = g / den;
#pragma unroll
  for (int i = 0; i < 2; ++i) {
#pragma unroll
    for (int r = 0; r < 16; ++r) {
      const int rloc = (r & 3) + 8 * (r >> 2) + 4 * h;
      const int row = wrp * 64 + i * 32 + rloc;
      const size_t idx = ((size_t)b * 512 + row) * 4096 + col;
      out[idx] = gil * acc[i][r] + x[idx];
    }
  }
}

extern "C" void kernel_launch(void* const* d_in, const int* in_sizes, int n_in,
                              void* d_out, int out_size, void* d_ws,
                              size_t ws_size, hipStream_t stream) {
  const float* x = (const float*)d_in[0];
  const float* Wq = (const float*)d_in[1];
  const float* bq = (const float*)d_in[2];
  const float* Wk = (const float*)d_in[3];
  const float* bk = (const float*)d_in[4];
  const float* Wv = (const float*)d_in[5];
  const float* bv = (const float*)d_in[6];
  const float* gamma = (const float*)d_in[7];
  float* out = (float*)d_out;

  char* ws = (char*)d_ws;
  u16* xT = (u16*)(ws);                    // 16,777,216 B : (B,N,C) bf16
  u16* wqk = (u16*)(ws + 16777216);        //    131,072 B
  u16* wv = (u16*)(ws + 16908288);         //    524,288 B
  u16* qb = (u16*)(ws + 17432576);         //  2,097,152 B : (B,N,64)
  u16* ktb = (u16*)(ws + 19529728);        //  2,097,152 B : (B,N,64)
  u8* v8 = (u8*)(ws + 21626880);           //  8,388,608 B : (B,C,N) e4m3
  // total ws use: 30,015,488 B

  k_transpose<<<dim3(128, 16, 4), 256, 0, stream>>>(x, xT);
  k_wcast<<<dim3(1280), 256, 0, stream>>>(Wq, Wk, Wv, wqk, wv);
  k_proj<<<dim3(32, 5, 4), 256, 0, stream>>>(xT, wqk, wv, bq, bk, bv,
                                             qb, ktb, v8);
  k_fused<<<dim3(256), 1024, 0, stream>>>(qb, ktb, v8, x, gamma, out);
}

// Round 10
// 197.932 us; speedup vs baseline: 1.3862x; 1.3862x over previous
//
#include <hip/hip_runtime.h>
#include <stdint.h>

// PAM module: B=4, C=512, N=4096, C8=64.
// R15: R14's v-direct-global broke coalescing (per-lane rows 4096B apart ->
// 32 cache lines/instr; hbm 377 GB/s, 164us). Falsifier fired: k_fused
// reverted to R13 (measured 88us). Residual analysis: total - k_fused is
// ~108us constant across R12-R14 -> shave fixed pipeline: k_transpose
// rewritten per G13 (float4 reads / ushort4 writes, 64x64 tiles; was 2B
// scalar stores). All numerics identical to R13.

typedef unsigned short u16;
typedef unsigned char u8;
typedef __attribute__((ext_vector_type(8))) short short8;  // 8 x bf16
typedef __attribute__((ext_vector_type(4))) float f32x4;
typedef __attribute__((ext_vector_type(16))) float f32x16;
typedef __attribute__((ext_vector_type(4))) int i32x4;
typedef __attribute__((ext_vector_type(8))) int i32x8;

#define ASYNC16(gp, lp)                                                        \
  __builtin_amdgcn_global_load_lds(                                            \
      (__attribute__((address_space(1))) void*)(void*)(gp),                    \
      (__attribute__((address_space(3))) void*)(lp), 16, 0, 0)

#define WAIT_VM0 0x0F70    // vmcnt==0, ignore exp/lgkm
#define WAIT_VM3 0x0F73    // vmcnt<=3
#define WAIT_LGKM0 0xC07F  // lgkmcnt==0

#define EXP_SHIFT 5.0f
#define EXP_CAP 57000.0f  // just under bf8 e5m2 max (57344)

__device__ __forceinline__ u16 f2bf(float f) {  // RNE float->bf16
  uint32_t u = __float_as_uint(f);
  u += 0x7FFFu + ((u >> 16) & 1u);
  return (u16)(u >> 16);
}

__device__ __forceinline__ u8 f2fp8(float f) {  // clamped e4m3
  f = fminf(fmaxf(f, -440.f), 440.f);
  int r = __builtin_amdgcn_cvt_pk_fp8_f32(f, f, 0, false);
  return (u8)(r & 0xFF);
}

// ---------------- transpose + cast: x (B,C,N) f32 -> xT (B,N,C) bf16 --------
// R15: 64x64 tiles, float4 coalesced reads (256B/row-group), ushort4
// coalesced writes (128B per bf16 row). LDS [64][65] pad -> write-phase
// column reads are 2-way bank aliasing (free, m136).
__global__ __launch_bounds__(256) void k_transpose(const float* __restrict__ x,
                                                   u16* __restrict__ xT) {
  __shared__ float tile[64][65];
  const int b = blockIdx.z;
  const int nb = blockIdx.x * 64;
  const int cb = blockIdx.y * 64;
  const int t = threadIdx.x;
  {
    const int nl = (t & 15) * 4, c0 = t >> 4;  // 16 c-rows per pass
    const float* xp = x + ((size_t)b * 512 + cb) * 4096 + nb;
#pragma unroll
    for (int p = 0; p < 4; ++p) {
      const int cl = c0 + p * 16;
      const float4 v = *(const float4*)(xp + (size_t)cl * 4096 + nl);
      tile[cl][nl] = v.x;
      tile[cl][nl + 1] = v.y;
      tile[cl][nl + 2] = v.z;
      tile[cl][nl + 3] = v.w;
    }
  }
  __syncthreads();
  {
    const int cl = (t & 15) * 4, n0 = t >> 4;  // 16 n-rows per pass
    u16* xtp = xT + ((size_t)b * 4096 + nb) * 512 + cb;
#pragma unroll
    for (int p = 0; p < 4; ++p) {
      const int nl = n0 + p * 16;
      ushort4 o;
      o.x = f2bf(tile[cl][nl]);
      o.y = f2bf(tile[cl + 1][nl]);
      o.z = f2bf(tile[cl + 2][nl]);
      o.w = f2bf(tile[cl + 3][nl]);
      *(ushort4*)(xtp + (size_t)nl * 512 + cl) = o;
    }
  }
}

// weights -> bf16. wqk = concat(Wq,Wk) (128x512), wv (512x512)
__global__ __launch_bounds__(256) void k_wcast(const float* __restrict__ Wq,
                                               const float* __restrict__ Wk,
                                               const float* __restrict__ Wv,
                                               u16* __restrict__ wqk,
                                               u16* __restrict__ wv) {
  const int idx = blockIdx.x * 256 + threadIdx.x;
  if (idx < 128 * 512) {
    const int r = idx >> 9, c = idx & 511;
    const float f = (r < 64) ? Wq[r * 512 + c] : Wk[(r - 64) * 512 + c];
    wqk[idx] = f2bf(f);
  } else {
    const int j = idx - 128 * 512;
    if (j < 512 * 512) wv[j] = f2bf(Wv[j]);
  }
}

// ------------- bf16 gemm_bt core: 128x128 tile, BK=64, swizzled LDS ---------
__device__ __forceinline__ void gemm_bt_tile(const u16* __restrict__ A,
                                             const u16* __restrict__ B,
                                             const int K, const int rowA0,
                                             const int colB0, u16* smem,
                                             f32x4 acc[4][4]) {
  const int t = threadIdx.x;
  const int lane = t & 63, wave = t >> 6;
  const int quad = lane >> 4, l15 = lane & 15;
  const int wr = wave >> 1, wc = wave & 1;
  u16* As = smem;          // [128][64] swizzled
  u16* Bs = smem + 8192;
  const f32x4 zero = {0.f, 0.f, 0.f, 0.f};
#pragma unroll
  for (int i = 0; i < 4; ++i)
#pragma unroll
    for (int j = 0; j < 4; ++j) acc[i][j] = zero;

  const int srow = t >> 3;                        // 0..31
  const int c8 = (lane & 7) ^ (lane >> 3);        // swizzled 16B chunk
  const u16* ga = A + (size_t)(rowA0 + srow) * K + c8 * 8;
  const u16* gb = B + (size_t)(colB0 + srow) * K + c8 * 8;
  char* la = (char*)As + wave * 1024;
  char* lb = (char*)Bs + wave * 1024;
  const size_t rK32 = (size_t)32 * K;

  const int sw0 = (quad) ^ (l15 & 7);
  const int sw1 = (4 + quad) ^ (l15 & 7);

  for (int k0 = 0; k0 < K; k0 += 64) {
    ASYNC16(ga + k0, la);
    ASYNC16(ga + k0 + rK32, la + 4096);
    ASYNC16(ga + k0 + 2 * rK32, la + 8192);
    ASYNC16(ga + k0 + 3 * rK32, la + 12288);
    ASYNC16(gb + k0, lb);
    ASYNC16(gb + k0 + rK32, lb + 4096);
    ASYNC16(gb + k0 + 2 * rK32, lb + 8192);
    ASYNC16(gb + k0 + 3 * rK32, lb + 12288);
    __syncthreads();
#pragma unroll
    for (int s = 0; s < 2; ++s) {
      const int sw = s ? sw1 : sw0;
      short8 a[4], b[4];
#pragma unroll
      for (int i = 0; i < 4; ++i)
        a[i] = *(const short8*)(As + (wr * 64 + i * 16 + l15) * 64 + sw * 8);
#pragma unroll
      for (int j = 0; j < 4; ++j)
        b[j] = *(const short8*)(Bs + (wc * 64 + j * 16 + l15) * 64 + sw * 8);
#pragma unroll
      for (int i = 0; i < 4; ++i)
#pragma unroll
        for (int j = 0; j < 4; ++j)
          acc[i][j] = __builtin_amdgcn_mfma_f32_16x16x32_bf16(a[i], b[j],
                                                              acc[i][j], 0, 0, 0);
    }
    __syncthreads();
  }
}

// ---- merged projections: by<4 -> v tile; by==4 -> qk tile ------------------
__global__ __launch_bounds__(256) void k_proj(const u16* __restrict__ xT,
                                              const u16* __restrict__ wqk,
                                              const u16* __restrict__ wv,
                                              const float* __restrict__ bq,
                                              const float* __restrict__ bk,
                                              const float* __restrict__ bv,
                                              u16* __restrict__ q,
                                              u16* __restrict__ kT,
                                              u8* __restrict__ v8) {
  __shared__ u16 smem[16384];
  const int b = blockIdx.z;
  const int by = blockIdx.y;
  const int t = threadIdx.x, lane = t & 63, wave = t >> 6;
  const int quad = lane >> 4, l15 = lane & 15;
  const int wr = wave >> 1, wc = wave & 1;
  f32x4 acc[4][4];

  if (by == 4) {  // q/k projection: C[n][o2] = xT @ wqk^T
    const int rowA0 = blockIdx.x * 128;
    gemm_bt_tile(xT + (size_t)b * 4096 * 512, wqk, 512, rowA0, 0, smem, acc);
#pragma unroll
    for (int j = 0; j < 4; ++j) {
      const int col = wc * 64 + j * 16 + l15;
      const float bias = (col < 64) ? bq[col] : bk[col - 64];
#pragma unroll
      for (int i = 0; i < 4; ++i) {
#pragma unroll
        for (int r = 0; r < 4; ++r) {
          const int row = rowA0 + wr * 64 + i * 16 + quad * 4 + r;
          const float val = acc[i][j][r] + bias;
          if (col < 64)
            q[((size_t)b * 4096 + row) * 64 + col] = f2bf(val);
          else
            kT[((size_t)b * 4096 + row) * 64 + (col - 64)] = f2bf(val);
        }
      }
    }
  } else {  // v projection: v8[c][n] = e4m3(Wv @ x + bv)
    const int rowA0 = by * 128;
    const int colB0 = blockIdx.x * 128;
    gemm_bt_tile(wv, xT + (size_t)b * 4096 * 512, 512, rowA0, colB0, smem, acc);
#pragma unroll
    for (int i = 0; i < 4; ++i) {
#pragma unroll
      for (int r = 0; r < 4; ++r) {
        const int row = rowA0 + wr * 64 + i * 16 + quad * 4 + r;
        const float bias = bv[row];
#pragma unroll
        for (int j = 0; j < 4; ++j) {
          const int col = colB0 + wc * 64 + j * 16 + l15;
          v8[((size_t)b * 512 + row) * 4096 + col] = f2fp8(acc[i][j][r] + bias);
        }
      }
    }
  }
}

// ---------------- fused attention+PV (16 waves, k-amortized QK) --------------
// R13 version verbatim (measured 88us). Per block: n-tile 128, c-half 256,
// one batch. m-loop 32 x 128. QK: wave (ms=w>>1: m-strip 16, nh=w&1:
// n-half 64): 2 k ds_reads + 8 MFMAs vs 8 register q frags. exp/pack:
// 4 strips -> P_lds[ms>>2], m-chunk (ms&3)^fbW. PV: wave grid 4x4,
// 4 mfma_scale 32x32x64 (A=v e4m3, B=P bf8). Staging: 3 ASYNC16/thread.
__global__ __launch_bounds__(1024, 4) void k_fused(
    const u16* __restrict__ q, const u16* __restrict__ kT,
    const u8* __restrict__ v8, const float* __restrict__ x,
    const float* __restrict__ gamma, float* __restrict__ out) {
  __shared__ u16 k_lds[2][128 * 64];    // 32 KB, k_attn swizzle
  __shared__ u8 v_lds[2][2][256 * 64];  // 64 KB [buf][ks][256 c][64 B]
  __shared__ u8 P_lds[2][128 * 64];     // 16 KB [ks][128 n][64 B] bf8
  __shared__ float lsum_lds[8][128];    // 4 KB per-m-strip partials

  const int t = threadIdx.x;
  const int l = t & 63, w = t >> 6;  // 16 waves
  const int quad = l >> 4, l15 = l & 15;
  const int l31 = l & 31, h = l >> 5;

  const int n0 = blockIdx.x * 128;
  const int c0 = blockIdx.y * 256;
  const int b = blockIdx.z;

  const u16* qg = q + ((size_t)b * 4096 + n0) * 64;
  const u16* kg = kT + (size_t)b * 4096 * 64;
  const u8* vg = v8 + ((size_t)b * 512 + c0) * 4096;

  // staging source addrs (LDS dst = wave-uniform base + lane*16)
  const int kr = t >> 3, kc = t & 7;  // k/q: 1024 chunks, 128B rows
  const u16* qsg = qg + kr * 64 + (kc ^ (kr & 7)) * 8;
  const u16* ksg = kg + kr * 64 + (kc ^ (kr & 7)) * 8;  // + m0*64
  const int vr = t >> 2, va = t & 3;  // v: 1024 chunks/ks, 64B rows
  const u8* vsg = vg + (size_t)vr * 4096 + (va ^ ((vr >> 1) & 3)) * 16;

#define STAGE_F(bi, m0)                                                        \
  do {                                                                         \
    ASYNC16(ksg + (size_t)(m0) * 64, (char*)k_lds[bi] + w * 1024);             \
    ASYNC16(vsg + (m0), (char*)v_lds[bi][0] + w * 1024);                       \
    ASYNC16(vsg + (m0) + 64, (char*)v_lds[bi][1] + w * 1024);                  \
  } while (0)

  // prologue: q into P_lds area, tile 0 into buf 0
  ASYNC16(qsg, (char*)P_lds[0] + w * 1024);
  STAGE_F(0, 0);
  __builtin_amdgcn_s_waitcnt(WAIT_VM3);  // q retired (tile0's 3 in flight)
  __builtin_amdgcn_s_barrier();
  asm volatile("" ::: "memory");
  const int ms = w >> 1, nh = w & 1;  // QK decomposition
  const int sw0 = quad ^ (l15 & 7);
  const int sw1 = (4 + quad) ^ (l15 & 7);
  short8 af[4][2];  // loop-invariant q fragments (strip s, sweep e)
#pragma unroll
  for (int s = 0; s < 4; ++s) {
    const u16* qrow = (const u16*)P_lds[0] + (nh * 64 + s * 16 + l15) * 64;
    af[s][0] = *(const short8*)(qrow + sw0 * 8);
    af[s][1] = *(const short8*)(qrow + sw1 * 8);
  }
  asm volatile("" ::: "memory");
  __builtin_amdgcn_s_waitcnt(WAIT_LGKM0);
  __builtin_amdgcn_s_barrier();  // q reads done -> P_lds writable
  asm volatile("" ::: "memory");

  // PV decomposition (k_pv layout), wave grid 4x4
  const int wrp = w >> 2, wcp = w & 3;
  int rowA[2], sA1[2], sA2[2];
#pragma unroll
  for (int i = 0; i < 2; ++i) {
    rowA[i] = wrp * 64 + i * 32 + l31;
    const int fa = (rowA[i] >> 1) & 3;
    sA1[i] = (2 * h) ^ fa;
    sA2[i] = (2 * h + 1) ^ fa;
  }
  const int rowB = wcp * 32 + l31;
  const int fbB = (rowB >> 1) & 3;
  const int sB1 = (2 * h) ^ fbB;
  const int sB2 = (2 * h + 1) ^ fbB;

  // P write base: ks = ms>>2, n-row nh*64 + s*16 + l15, m-chunk (ms&3)^fbW
  const int fbW = (l15 >> 1) & 3;
  u8* Pwbase = P_lds[ms >> 2] + (nh * 64 + l15) * 64 +
               (((ms & 3) ^ fbW) * 16) + quad * 4;

  const int krow_off = (ms * 16 + l15) * 64;  // k read row offset (u16)

  f32x16 acc[2];
#pragma unroll
  for (int i = 0; i < 2; ++i)
#pragma unroll
    for (int r = 0; r < 16; ++r) acc[i][r] = 0.f;

  float lsums[4] = {0.f, 0.f, 0.f, 0.f};
  const f32x4 zero = {0.f, 0.f, 0.f, 0.f};

  for (int it = 0; it < 32; ++it) {
    __builtin_amdgcn_s_waitcnt(WAIT_VM0);  // tile-it staged
    asm volatile("" ::: "memory");
    __builtin_amdgcn_s_barrier();
    asm volatile("" ::: "memory");
    const int cur = it & 1;
    if (it + 1 < 32) STAGE_F(cur ^ 1, (it + 1) * 128);

    // ---- QK: e[m(wave's 16)][n(wave's 64)], k read once, q from regs ----
    const u16* kb = k_lds[cur];
    const short8 kf0 = *(const short8*)(kb + krow_off + sw0 * 8);
    const short8 kf1 = *(const short8*)(kb + krow_off + sw1 * 8);
    f32x4 eacc[4];
#pragma unroll
    for (int s = 0; s < 4; ++s) eacc[s] = zero;
    __builtin_amdgcn_s_setprio(1);
#pragma unroll
    for (int s = 0; s < 4; ++s)
      eacc[s] = __builtin_amdgcn_mfma_f32_16x16x32_bf16(kf0, af[s][0],
                                                        eacc[s], 0, 0, 0);
#pragma unroll
    for (int s = 0; s < 4; ++s)
      eacc[s] = __builtin_amdgcn_mfma_f32_16x16x32_bf16(kf1, af[s][1],
                                                        eacc[s], 0, 0, 0);
    __builtin_amdgcn_s_setprio(0);

    // ---- exp -> bf8 -> P_lds, per-strip lsums ----
#pragma unroll
    for (int s = 0; s < 4; ++s) {
      const float e0 = fminf(__expf(eacc[s][0] - EXP_SHIFT), EXP_CAP);
      const float e1 = fminf(__expf(eacc[s][1] - EXP_SHIFT), EXP_CAP);
      const float e2 = fminf(__expf(eacc[s][2] - EXP_SHIFT), EXP_CAP);
      const float e3 = fminf(__expf(eacc[s][3] - EXP_SHIFT), EXP_CAP);
      lsums[s] += (e0 + e1) + (e2 + e3);
      int pk = __builtin_amdgcn_cvt_pk_bf8_f32(e0, e1, 0, false);
      pk = __builtin_amdgcn_cvt_pk_bf8_f32(e2, e3, pk, true);
      *(int*)(Pwbase + s * 1024) = pk;  // row step 16 rows * 64B
    }
    asm volatile("" ::: "memory");
    __builtin_amdgcn_s_waitcnt(WAIT_LGKM0);
    __builtin_amdgcn_s_barrier();  // P tile complete, visible to all waves
    asm volatile("" ::: "memory");

    // ---- PV: acc += v_tile(e4m3) @ P^T(bf8), 2 k-steps of 64 ----
#pragma unroll
    for (int ks = 0; ks < 2; ++ks) {
      const u8* Vb = v_lds[cur][ks];
      const u8* Pb = P_lds[ks];
      i32x8 bb;
      {
        const u8* pb = Pb + rowB * 64;
        const i32x4 blo = *(const i32x4*)(pb + sB1 * 16);
        const i32x4 bhi = *(const i32x4*)(pb + sB2 * 16);
        bb[0] = blo[0]; bb[1] = blo[1]; bb[2] = blo[2]; bb[3] = blo[3];
        bb[4] = bhi[0]; bb[5] = bhi[1]; bb[6] = bhi[2]; bb[7] = bhi[3];
      }
      __builtin_amdgcn_s_setprio(1);
#pragma unroll
      for (int i = 0; i < 2; ++i) {
        const u8* pa = Vb + rowA[i] * 64;
        const i32x4 lo = *(const i32x4*)(pa + sA1[i] * 16);
        const i32x4 hi = *(const i32x4*)(pa + sA2[i] * 16);
        i32x8 a;
        a[0] = lo[0]; a[1] = lo[1]; a[2] = lo[2]; a[3] = lo[3];
        a[4] = hi[0]; a[5] = hi[1]; a[6] = hi[2]; a[7] = hi[3];
        acc[i] = __builtin_amdgcn_mfma_scale_f32_32x32x64_f8f6f4(
            a, bb, acc[i], 0 /*A=e4m3*/, 1 /*B=bf8*/, 0, 0x7F, 0, 0x7F);
      }
      __builtin_amdgcn_s_setprio(0);
    }
    asm volatile("" ::: "memory");
  }
#undef STAGE_F

  // ---- lsum reduce: quad-sum per (strip, l15), store per m-strip ----
#pragma unroll
  for (int s = 0; s < 4; ++s) {
    lsums[s] += __shfl_xor(lsums[s], 16);
    lsums[s] += __shfl_xor(lsums[s], 32);
  }
  if (l < 16) {
#pragma unroll
    for (int s = 0; s < 4; ++s)
      lsum_lds[ms][nh * 64 + s * 16 + l] = lsums[s];
  }
  asm volatile("" ::: "memory");
  __builtin_amdgcn_s_waitcnt(WAIT_LGKM0);
  __builtin_amdgcn_s_barrier();
  asm volatile("" ::: "memory");

  // ---- epilogue: out = gamma/lsum[n] * acc + x ----
  const float g = gamma[0];
  const int col = n0 + wcp * 32 + l31;
  const int nc = wcp * 32 + l31;
  float den = 0.f;
#pragma unroll
  for (int m = 0; m < 8; ++m) den += lsum_lds[m][nc];
  const float gil = g / den;
#pragma unroll
  for (int i = 0; i < 2; ++i) {
#pragma unroll
    for (int r = 0; r < 16; ++r) {
      const int rloc = (r & 3) + 8 * (r >> 2) + 4 * h;
      const int row = c0 + wrp * 64 + i * 32 + rloc;
      const size_t idx = ((size_t)b * 512 + row) * 4096 + col;
      out[idx] = gil * acc[i][r] + x[idx];
    }
  }
}

extern "C" void kernel_launch(void* const* d_in, const int* in_sizes, int n_in,
                              void* d_out, int out_size, void* d_ws,
                              size_t ws_size, hipStream_t stream) {
  const float* x = (const float*)d_in[0];
  const float* Wq = (const float*)d_in[1];
  const float* bq = (const float*)d_in[2];
  const float* Wk = (const float*)d_in[3];
  const float* bk = (const float*)d_in[4];
  const float* Wv = (const float*)d_in[5];
  const float* bv = (const float*)d_in[6];
  const float* gamma = (const float*)d_in[7];
  float* out = (float*)d_out;

  char* ws = (char*)d_ws;
  u16* xT = (u16*)(ws);                    // 16,777,216 B : (B,N,C) bf16
  u16* wqk = (u16*)(ws + 16777216);        //    131,072 B
  u16* wv = (u16*)(ws + 16908288);         //    524,288 B
  u16* qb = (u16*)(ws + 17432576);         //  2,097,152 B : (B,N,64)
  u16* ktb = (u16*)(ws + 19529728);        //  2,097,152 B : (B,N,64)
  u8* v8 = (u8*)(ws + 21626880);           //  8,388,608 B : (B,C,N) e4m3
  // total ws use: 30,015,488 B

  k_transpose<<<dim3(64, 8, 4), 256, 0, stream>>>(x, xT);
  k_wcast<<<dim3(1280), 256, 0, stream>>>(Wq, Wk, Wv, wqk, wv);
  k_proj<<<dim3(32, 5, 4), 256, 0, stream>>>(xT, wqk, wv, bq, bk, bv,
                                             qb, ktb, v8);
  k_fused<<<dim3(32, 2, 4), 1024, 0, stream>>>(qb, ktb, v8, x, gamma, out);
}

// Round 11
// 189.816 us; speedup vs baseline: 1.4455x; 1.0428x over previous
//
#include <hip/hip_runtime.h>
#include <stdint.h>

// PAM module: B=4, C=512, N=4096, C8=64.
// R16: residual (total - k_fused ~= 109us, 5 rounds invariant) attributed to
// k_proj's 2-barrier K=512 GEMM structure (vmcnt(0)+syncthreads drain per
// iter). Applied the R6 recipe (proven 2.2x on k_attn): 512 thr / 8 waves
// (4/SIMD), 2 blocks/CU, double-buffered 64KB LDS, raw s_barrier + counted
// vmcnt(4) (drain only at tail). Same tile/swizzle/MFMA order -> outputs
// bit-identical. k_fused = R13 verbatim (88.7us measured).

typedef unsigned short u16;
typedef unsigned char u8;
typedef __attribute__((ext_vector_type(8))) short short8;  // 8 x bf16
typedef __attribute__((ext_vector_type(4))) float f32x4;
typedef __attribute__((ext_vector_type(16))) float f32x16;
typedef __attribute__((ext_vector_type(4))) int i32x4;
typedef __attribute__((ext_vector_type(8))) int i32x8;

#define ASYNC16(gp, lp)                                                        \
  __builtin_amdgcn_global_load_lds(                                            \
      (__attribute__((address_space(1))) void*)(void*)(gp),                    \
      (__attribute__((address_space(3))) void*)(lp), 16, 0, 0)

#define WAIT_VM0 0x0F70    // vmcnt==0, ignore exp/lgkm
#define WAIT_VM3 0x0F73    // vmcnt<=3
#define WAIT_VM4 0x0F74    // vmcnt<=4
#define WAIT_LGKM0 0xC07F  // lgkmcnt==0

#define EXP_SHIFT 5.0f
#define EXP_CAP 57000.0f  // just under bf8 e5m2 max (57344)

__device__ __forceinline__ u16 f2bf(float f) {  // RNE float->bf16
  uint32_t u = __float_as_uint(f);
  u += 0x7FFFu + ((u >> 16) & 1u);
  return (u16)(u >> 16);
}

__device__ __forceinline__ u8 f2fp8(float f) {  // clamped e4m3
  f = fminf(fmaxf(f, -440.f), 440.f);
  int r = __builtin_amdgcn_cvt_pk_fp8_f32(f, f, 0, false);
  return (u8)(r & 0xFF);
}

// ---------------- transpose + cast: x (B,C,N) f32 -> xT (B,N,C) bf16 --------
__global__ __launch_bounds__(256) void k_transpose(const float* __restrict__ x,
                                                   u16* __restrict__ xT) {
  __shared__ float tile[64][65];
  const int b = blockIdx.z;
  const int nb = blockIdx.x * 64;
  const int cb = blockIdx.y * 64;
  const int t = threadIdx.x;
  {
    const int nl = (t & 15) * 4, c0 = t >> 4;  // 16 c-rows per pass
    const float* xp = x + ((size_t)b * 512 + cb) * 4096 + nb;
#pragma unroll
    for (int p = 0; p < 4; ++p) {
      const int cl = c0 + p * 16;
      const float4 v = *(const float4*)(xp + (size_t)cl * 4096 + nl);
      tile[cl][nl] = v.x;
      tile[cl][nl + 1] = v.y;
      tile[cl][nl + 2] = v.z;
      tile[cl][nl + 3] = v.w;
    }
  }
  __syncthreads();
  {
    const int cl = (t & 15) * 4, n0 = t >> 4;  // 16 n-rows per pass
    u16* xtp = xT + ((size_t)b * 4096 + nb) * 512 + cb;
#pragma unroll
    for (int p = 0; p < 4; ++p) {
      const int nl = n0 + p * 16;
      ushort4 o;
      o.x = f2bf(tile[cl][nl]);
      o.y = f2bf(tile[cl + 1][nl]);
      o.z = f2bf(tile[cl + 2][nl]);
      o.w = f2bf(tile[cl + 3][nl]);
      *(ushort4*)(xtp + (size_t)nl * 512 + cl) = o;
    }
  }
}

// weights -> bf16. wqk = concat(Wq,Wk) (128x512), wv (512x512)
__global__ __launch_bounds__(256) void k_wcast(const float* __restrict__ Wq,
                                               const float* __restrict__ Wk,
                                               const float* __restrict__ Wv,
                                               u16* __restrict__ wqk,
                                               u16* __restrict__ wv) {
  const int idx = blockIdx.x * 256 + threadIdx.x;
  if (idx < 128 * 512) {
    const int r = idx >> 9, c = idx & 511;
    const float f = (r < 64) ? Wq[r * 512 + c] : Wk[(r - 64) * 512 + c];
    wqk[idx] = f2bf(f);
  } else {
    const int j = idx - 128 * 512;
    if (j < 512 * 512) wv[j] = f2bf(Wv[j]);
  }
}

// ------ bf16 gemm_bt core, R16: 8 waves, dbuf, counted vmcnt, 128x128 -------
// Wave grid 2x4 (wr: 64 rows, wc: 32 cols), acc[4][2]. Each wave stages
// rows [w*8, w*8+8) and [64+w*8, ...) of both A and B tiles (4 ASYNC16 per
// thread per K-tile). vmcnt(4) keeps the next tile's loads in flight across
// barriers; drain only at the tail. K-tile / sweep order identical to the
// old gemm_bt_tile -> bit-identical accumulation.
__device__ __forceinline__ void gemm8_bt(const u16* __restrict__ A,
                                         const u16* __restrict__ B,
                                         const int K, const int rowA0,
                                         const int colB0, u16* smem,
                                         f32x4 acc[4][2]) {
  const int t = threadIdx.x;
  const int lane = t & 63, w = t >> 6;   // 8 waves
  const int quad = lane >> 4, l15 = lane & 15;
  const int wr = w >> 2, wc = w & 3;     // 2 x 4 wave grid
  const f32x4 zero = {0.f, 0.f, 0.f, 0.f};
#pragma unroll
  for (int i = 0; i < 4; ++i)
#pragma unroll
    for (int j = 0; j < 2; ++j) acc[i][j] = zero;

  const int srow = t >> 3;                  // 0..63
  const int c8 = (lane & 7) ^ (lane >> 3);  // swizzled 16B chunk (row&7 = lane>>3)
  const u16* ga = A + (size_t)(rowA0 + srow) * K + c8 * 8;
  const u16* gb = B + (size_t)(colB0 + srow) * K + c8 * 8;
  const size_t rK64 = (size_t)64 * K;

  // byte layout: [buf][A 16KB | B 16KB]
#define STAGE_G(bi, k0)                                                        \
  do {                                                                         \
    char* Ab = (char*)smem + (bi) * 32768 + w * 1024;                          \
    char* Bb = (char*)smem + (bi) * 32768 + 16384 + w * 1024;                  \
    ASYNC16(ga + (k0), Ab);                                                    \
    ASYNC16(ga + (k0) + rK64, Ab + 8192);                                      \
    ASYNC16(gb + (k0), Bb);                                                    \
    ASYNC16(gb + (k0) + rK64, Bb + 8192);                                      \
  } while (0)

  const int sw0 = (quad) ^ (l15 & 7);
  const int sw1 = (4 + quad) ^ (l15 & 7);

  const int nIt = K >> 6;  // K/64 tiles
  STAGE_G(0, 0);
  STAGE_G(1, 64);

  for (int it = 0; it < nIt; ++it) {
    if (it < nIt - 1)
      __builtin_amdgcn_s_waitcnt(WAIT_VM4);  // tile-it's 4 retired
    else
      __builtin_amdgcn_s_waitcnt(WAIT_VM0);
    asm volatile("" ::: "memory");
    __builtin_amdgcn_s_barrier();  // all waves' tile-it slices in LDS
    asm volatile("" ::: "memory");

    const u16* As = smem + (it & 1) * 16384;
    const u16* Bs = As + 8192;
#pragma unroll
    for (int s = 0; s < 2; ++s) {
      const int sw = s ? sw1 : sw0;
      short8 a[4], b[2];
#pragma unroll
      for (int i = 0; i < 4; ++i)
        a[i] = *(const short8*)(As + (wr * 64 + i * 16 + l15) * 64 + sw * 8);
#pragma unroll
      for (int j = 0; j < 2; ++j)
        b[j] = *(const short8*)(Bs + (wc * 32 + j * 16 + l15) * 64 + sw * 8);
      __builtin_amdgcn_s_setprio(1);
#pragma unroll
      for (int i = 0; i < 4; ++i)
#pragma unroll
        for (int j = 0; j < 2; ++j)
          acc[i][j] = __builtin_amdgcn_mfma_f32_16x16x32_bf16(a[i], b[j],
                                                              acc[i][j], 0, 0, 0);
      __builtin_amdgcn_s_setprio(0);
    }
    asm volatile("" ::: "memory");
    __builtin_amdgcn_s_barrier();  // all waves done reading buf (it&1)
    asm volatile("" ::: "memory");
    if (it + 2 < nIt) STAGE_G(it & 1, (it + 2) * 64);
  }
#undef STAGE_G
}

// ---- merged projections: by<4 -> v tile; by==4 -> qk tile (512 thr) --------
__global__ __launch_bounds__(512, 4) void k_proj(const u16* __restrict__ xT,
                                                 const u16* __restrict__ wqk,
                                                 const u16* __restrict__ wv,
                                                 const float* __restrict__ bq,
                                                 const float* __restrict__ bk,
                                                 const float* __restrict__ bv,
                                                 u16* __restrict__ q,
                                                 u16* __restrict__ kT,
                                                 u8* __restrict__ v8) {
  __shared__ u16 smem[32768];  // 64 KB: 2 x (A 16KB | B 16KB)
  const int b = blockIdx.z;
  const int by = blockIdx.y;
  const int t = threadIdx.x, lane = t & 63, w = t >> 6;
  const int quad = lane >> 4, l15 = lane & 15;
  const int wr = w >> 2, wc = w & 3;
  f32x4 acc[4][2];

  if (by == 4) {  // q/k projection: C[n][o2] = xT @ wqk^T
    const int rowA0 = blockIdx.x * 128;
    gemm8_bt(xT + (size_t)b * 4096 * 512, wqk, 512, rowA0, 0, smem, acc);
#pragma unroll
    for (int j = 0; j < 2; ++j) {
      const int col = wc * 32 + j * 16 + l15;
      const float bias = (col < 64) ? bq[col] : bk[col - 64];
#pragma unroll
      for (int i = 0; i < 4; ++i) {
#pragma unroll
        for (int r = 0; r < 4; ++r) {
          const int row = rowA0 + wr * 64 + i * 16 + quad * 4 + r;
          const float val = acc[i][j][r] + bias;
          if (col < 64)
            q[((size_t)b * 4096 + row) * 64 + col] = f2bf(val);
          else
            kT[((size_t)b * 4096 + row) * 64 + (col - 64)] = f2bf(val);
        }
      }
    }
  } else {  // v projection: v8[c][n] = e4m3(Wv @ x + bv)
    const int rowA0 = by * 128;
    const int colB0 = blockIdx.x * 128;
    gemm8_bt(wv, xT + (size_t)b * 4096 * 512, 512, rowA0, colB0, smem, acc);
#pragma unroll
    for (int i = 0; i < 4; ++i) {
#pragma unroll
      for (int r = 0; r < 4; ++r) {
        const int row = rowA0 + wr * 64 + i * 16 + quad * 4 + r;
        const float bias = bv[row];
#pragma unroll
        for (int j = 0; j < 2; ++j) {
          const int col = colB0 + wc * 32 + j * 16 + l15;
          v8[((size_t)b * 512 + row) * 4096 + col] = f2fp8(acc[i][j][r] + bias);
        }
      }
    }
  }
}

// ---------------- fused attention+PV (16 waves, k-amortized QK) --------------
// R13 version verbatim (measured 88.7us).
__global__ __launch_bounds__(1024, 4) void k_fused(
    const u16* __restrict__ q, const u16* __restrict__ kT,
    const u8* __restrict__ v8, const float* __restrict__ x,
    const float* __restrict__ gamma, float* __restrict__ out) {
  __shared__ u16 k_lds[2][128 * 64];    // 32 KB, k_attn swizzle
  __shared__ u8 v_lds[2][2][256 * 64];  // 64 KB [buf][ks][256 c][64 B]
  __shared__ u8 P_lds[2][128 * 64];     // 16 KB [ks][128 n][64 B] bf8
  __shared__ float lsum_lds[8][128];    // 4 KB per-m-strip partials

  const int t = threadIdx.x;
  const int l = t & 63, w = t >> 6;  // 16 waves
  const int quad = l >> 4, l15 = l & 15;
  const int l31 = l & 31, h = l >> 5;

  const int n0 = blockIdx.x * 128;
  const int c0 = blockIdx.y * 256;
  const int b = blockIdx.z;

  const u16* qg = q + ((size_t)b * 4096 + n0) * 64;
  const u16* kg = kT + (size_t)b * 4096 * 64;
  const u8* vg = v8 + ((size_t)b * 512 + c0) * 4096;

  // staging source addrs (LDS dst = wave-uniform base + lane*16)
  const int kr = t >> 3, kc = t & 7;  // k/q: 1024 chunks, 128B rows
  const u16* qsg = qg + kr * 64 + (kc ^ (kr & 7)) * 8;
  const u16* ksg = kg + kr * 64 + (kc ^ (kr & 7)) * 8;  // + m0*64
  const int vr = t >> 2, va = t & 3;  // v: 1024 chunks/ks, 64B rows
  const u8* vsg = vg + (size_t)vr * 4096 + (va ^ ((vr >> 1) & 3)) * 16;

#define STAGE_F(bi, m0)                                                        \
  do {                                                                         \
    ASYNC16(ksg + (size_t)(m0) * 64, (char*)k_lds[bi] + w * 1024);             \
    ASYNC16(vsg + (m0), (char*)v_lds[bi][0] + w * 1024);                       \
    ASYNC16(vsg + (m0) + 64, (char*)v_lds[bi][1] + w * 1024);                  \
  } while (0)

  // prologue: q into P_lds area, tile 0 into buf 0
  ASYNC16(qsg, (char*)P_lds[0] + w * 1024);
  STAGE_F(0, 0);
  __builtin_amdgcn_s_waitcnt(WAIT_VM3);  // q retired (tile0's 3 in flight)
  __builtin_amdgcn_s_barrier();
  asm volatile("" ::: "memory");
  const int ms = w >> 1, nh = w & 1;  // QK decomposition
  const int sw0 = quad ^ (l15 & 7);
  const int sw1 = (4 + quad) ^ (l15 & 7);
  short8 af[4][2];  // loop-invariant q fragments (strip s, sweep e)
#pragma unroll
  for (int s = 0; s < 4; ++s) {
    const u16* qrow = (const u16*)P_lds[0] + (nh * 64 + s * 16 + l15) * 64;
    af[s][0] = *(const short8*)(qrow + sw0 * 8);
    af[s][1] = *(const short8*)(qrow + sw1 * 8);
  }
  asm volatile("" ::: "memory");
  __builtin_amdgcn_s_waitcnt(WAIT_LGKM0);
  __builtin_amdgcn_s_barrier();  // q reads done -> P_lds writable
  asm volatile("" ::: "memory");

  // PV decomposition (k_pv layout), wave grid 4x4
  const int wrp = w >> 2, wcp = w & 3;
  int rowA[2], sA1[2], sA2[2];
#pragma unroll
  for (int i = 0; i < 2; ++i) {
    rowA[i] = wrp * 64 + i * 32 + l31;
    const int fa = (rowA[i] >> 1) & 3;
    sA1[i] = (2 * h) ^ fa;
    sA2[i] = (2 * h + 1) ^ fa;
  }
  const int rowB = wcp * 32 + l31;
  const int fbB = (rowB >> 1) & 3;
  const int sB1 = (2 * h) ^ fbB;
  const int sB2 = (2 * h + 1) ^ fbB;

  // P write base: ks = ms>>2, n-row nh*64 + s*16 + l15, m-chunk (ms&3)^fbW
  const int fbW = (l15 >> 1) & 3;
  u8* Pwbase = P_lds[ms >> 2] + (nh * 64 + l15) * 64 +
               (((ms & 3) ^ fbW) * 16) + quad * 4;

  const int krow_off = (ms * 16 + l15) * 64;  // k read row offset (u16)

  f32x16 acc[2];
#pragma unroll
  for (int i = 0; i < 2; ++i)
#pragma unroll
    for (int r = 0; r < 16; ++r) acc[i][r] = 0.f;

  float lsums[4] = {0.f, 0.f, 0.f, 0.f};
  const f32x4 zero = {0.f, 0.f, 0.f, 0.f};

  for (int it = 0; it < 32; ++it) {
    __builtin_amdgcn_s_waitcnt(WAIT_VM0);  // tile-it staged
    asm volatile("" ::: "memory");
    __builtin_amdgcn_s_barrier();
    asm volatile("" ::: "memory");
    const int cur = it & 1;
    if (it + 1 < 32) STAGE_F(cur ^ 1, (it + 1) * 128);

    // ---- QK: e[m(wave's 16)][n(wave's 64)], k read once, q from regs ----
    const u16* kb = k_lds[cur];
    const short8 kf0 = *(const short8*)(kb + krow_off + sw0 * 8);
    const short8 kf1 = *(const short8*)(kb + krow_off + sw1 * 8);
    f32x4 eacc[4];
#pragma unroll
    for (int s = 0; s < 4; ++s) eacc[s] = zero;
    __builtin_amdgcn_s_setprio(1);
#pragma unroll
    for (int s = 0; s < 4; ++s)
      eacc[s] = __builtin_amdgcn_mfma_f32_16x16x32_bf16(kf0, af[s][0],
                                                        eacc[s], 0, 0, 0);
#pragma unroll
    for (int s = 0; s < 4; ++s)
      eacc[s] = __builtin_amdgcn_mfma_f32_16x16x32_bf16(kf1, af[s][1],
                                                        eacc[s], 0, 0, 0);
    __builtin_amdgcn_s_setprio(0);

    // ---- exp -> bf8 -> P_lds, per-strip lsums ----
#pragma unroll
    for (int s = 0; s < 4; ++s) {
      const float e0 = fminf(__expf(eacc[s][0] - EXP_SHIFT), EXP_CAP);
      const float e1 = fminf(__expf(eacc[s][1] - EXP_SHIFT), EXP_CAP);
      const float e2 = fminf(__expf(eacc[s][2] - EXP_SHIFT), EXP_CAP);
      const float e3 = fminf(__expf(eacc[s][3] - EXP_SHIFT), EXP_CAP);
      lsums[s] += (e0 + e1) + (e2 + e3);
      int pk = __builtin_amdgcn_cvt_pk_bf8_f32(e0, e1, 0, false);
      pk = __builtin_amdgcn_cvt_pk_bf8_f32(e2, e3, pk, true);
      *(int*)(Pwbase + s * 1024) = pk;  // row step 16 rows * 64B
    }
    asm volatile("" ::: "memory");
    __builtin_amdgcn_s_waitcnt(WAIT_LGKM0);
    __builtin_amdgcn_s_barrier();  // P tile complete, visible to all waves
    asm volatile("" ::: "memory");

    // ---- PV: acc += v_tile(e4m3) @ P^T(bf8), 2 k-steps of 64 ----
#pragma unroll
    for (int ks = 0; ks < 2; ++ks) {
      const u8* Vb = v_lds[cur][ks];
      const u8* Pb = P_lds[ks];
      i32x8 bb;
      {
        const u8* pb = Pb + rowB * 64;
        const i32x4 blo = *(const i32x4*)(pb + sB1 * 16);
        const i32x4 bhi = *(const i32x4*)(pb + sB2 * 16);
        bb[0] = blo[0]; bb[1] = blo[1]; bb[2] = blo[2]; bb[3] = blo[3];
        bb[4] = bhi[0]; bb[5] = bhi[1]; bb[6] = bhi[2]; bb[7] = bhi[3];
      }
      __builtin_amdgcn_s_setprio(1);
#pragma unroll
      for (int i = 0; i < 2; ++i) {
        const u8* pa = Vb + rowA[i] * 64;
        const i32x4 lo = *(const i32x4*)(pa + sA1[i] * 16);
        const i32x4 hi = *(const i32x4*)(pa + sA2[i] * 16);
        i32x8 a;
        a[0] = lo[0]; a[1] = lo[1]; a[2] = lo[2]; a[3] = lo[3];
        a[4] = hi[0]; a[5] = hi[1]; a[6] = hi[2]; a[7] = hi[3];
        acc[i] = __builtin_amdgcn_mfma_scale_f32_32x32x64_f8f6f4(
            a, bb, acc[i], 0 /*A=e4m3*/, 1 /*B=bf8*/, 0, 0x7F, 0, 0x7F);
      }
      __builtin_amdgcn_s_setprio(0);
    }
    asm volatile("" ::: "memory");
  }
#undef STAGE_F

  // ---- lsum reduce: quad-sum per (strip, l15), store per m-strip ----
#pragma unroll
  for (int s = 0; s < 4; ++s) {
    lsums[s] += __shfl_xor(lsums[s], 16);
    lsums[s] += __shfl_xor(lsums[s], 32);
  }
  if (l < 16) {
#pragma unroll
    for (int s = 0; s < 4; ++s)
      lsum_lds[ms][nh * 64 + s * 16 + l] = lsums[s];
  }
  asm volatile("" ::: "memory");
  __builtin_amdgcn_s_waitcnt(WAIT_LGKM0);
  __builtin_amdgcn_s_barrier();
  asm volatile("" ::: "memory");

  // ---- epilogue: out = gamma/lsum[n] * acc + x ----
  const float g = gamma[0];
  const int col = n0 + wcp * 32 + l31;
  const int nc = wcp * 32 + l31;
  float den = 0.f;
#pragma unroll
  for (int m = 0; m < 8; ++m) den += lsum_lds[m][nc];
  const float gil = g / den;
#pragma unroll
  for (int i = 0; i < 2; ++i) {
#pragma unroll
    for (int r = 0; r < 16; ++r) {
      const int rloc = (r & 3) + 8 * (r >> 2) + 4 * h;
      const int row = c0 + wrp * 64 + i * 32 + rloc;
      const size_t idx = ((size_t)b * 512 + row) * 4096 + col;
      out[idx] = gil * acc[i][r] + x[idx];
    }
  }
}

extern "C" void kernel_launch(void* const* d_in, const int* in_sizes, int n_in,
                              void* d_out, int out_size, void* d_ws,
                              size_t ws_size, hipStream_t stream) {
  const float* x = (const float*)d_in[0];
  const float* Wq = (const float*)d_in[1];
  const float* bq = (const float*)d_in[2];
  const float* Wk = (const float*)d_in[3];
  const float* bk = (const float*)d_in[4];
  const float* Wv = (const float*)d_in[5];
  const float* bv = (const float*)d_in[6];
  const float* gamma = (const float*)d_in[7];
  float* out = (float*)d_out;

  char* ws = (char*)d_ws;
  u16* xT = (u16*)(ws);                    // 16,777,216 B : (B,N,C) bf16
  u16* wqk = (u16*)(ws + 16777216);        //    131,072 B
  u16* wv = (u16*)(ws + 16908288);         //    524,288 B
  u16* qb = (u16*)(ws + 17432576);         //  2,097,152 B : (B,N,64)
  u16* ktb = (u16*)(ws + 19529728);        //  2,097,152 B : (B,N,64)
  u8* v8 = (u8*)(ws + 21626880);           //  8,388,608 B : (B,C,N) e4m3
  // total ws use: 30,015,488 B

  k_transpose<<<dim3(64, 8, 4), 256, 0, stream>>>(x, xT);
  k_wcast<<<dim3(1280), 256, 0, stream>>>(Wq, Wk, Wv, wqk, wv);
  k_proj<<<dim3(32, 5, 4), 512, 0, stream>>>(xT, wqk, wv, bq, bk, bv,
                                             qb, ktb, v8);
  k_fused<<<dim3(32, 2, 4), 1024, 0, stream>>>(qb, ktb, v8, x, gamma, out);
}

// Round 12
// 180.183 us; speedup vs baseline: 1.5228x; 1.0535x over previous
//
#include <hip/hip_runtime.h>
#include <stdint.h>

// PAM module: B=4, C=512, N=4096, C8=64.
// R17: k_fused phases serialized (QK->exp->barrier->PV, 2 barriers/iter;
// no pipe >40%). Software-pipelined to ONE barrier/iter: double-buffered P
// (LDS 132KB), interval j = {sync; stage v(j),k(j+1); QK(j)+exp(j)->P[j&1];
// PV(j-1)}. PV(j-1) independent of QK/exp(j) -> MFMA/VALU overlap in the
// single barrier-free region. Layout/math bit-identical to R13.
// k_proj = R16 (8-wave counted-vmcnt, +8us proven).

typedef unsigned short u16;
typedef unsigned char u8;
typedef __attribute__((ext_vector_type(8))) short short8;  // 8 x bf16
typedef __attribute__((ext_vector_type(4))) float f32x4;
typedef __attribute__((ext_vector_type(16))) float f32x16;
typedef __attribute__((ext_vector_type(4))) int i32x4;
typedef __attribute__((ext_vector_type(8))) int i32x8;

#define ASYNC16(gp, lp)                                                        \
  __builtin_amdgcn_global_load_lds(                                            \
      (__attribute__((address_space(1))) void*)(void*)(gp),                    \
      (__attribute__((address_space(3))) void*)(lp), 16, 0, 0)

#define WAIT_VM0 0x0F70    // vmcnt==0, ignore exp/lgkm
#define WAIT_VM4 0x0F74    // vmcnt<=4
#define WAIT_LGKM0 0xC07F  // lgkmcnt==0

#define EXP_SHIFT 5.0f
#define EXP_CAP 57000.0f  // just under bf8 e5m2 max (57344)

__device__ __forceinline__ u16 f2bf(float f) {  // RNE float->bf16
  uint32_t u = __float_as_uint(f);
  u += 0x7FFFu + ((u >> 16) & 1u);
  return (u16)(u >> 16);
}

__device__ __forceinline__ u8 f2fp8(float f) {  // clamped e4m3
  f = fminf(fmaxf(f, -440.f), 440.f);
  int r = __builtin_amdgcn_cvt_pk_fp8_f32(f, f, 0, false);
  return (u8)(r & 0xFF);
}

// ---------------- transpose + cast: x (B,C,N) f32 -> xT (B,N,C) bf16 --------
__global__ __launch_bounds__(256) void k_transpose(const float* __restrict__ x,
                                                   u16* __restrict__ xT) {
  __shared__ float tile[64][65];
  const int b = blockIdx.z;
  const int nb = blockIdx.x * 64;
  const int cb = blockIdx.y * 64;
  const int t = threadIdx.x;
  {
    const int nl = (t & 15) * 4, c0 = t >> 4;  // 16 c-rows per pass
    const float* xp = x + ((size_t)b * 512 + cb) * 4096 + nb;
#pragma unroll
    for (int p = 0; p < 4; ++p) {
      const int cl = c0 + p * 16;
      const float4 v = *(const float4*)(xp + (size_t)cl * 4096 + nl);
      tile[cl][nl] = v.x;
      tile[cl][nl + 1] = v.y;
      tile[cl][nl + 2] = v.z;
      tile[cl][nl + 3] = v.w;
    }
  }
  __syncthreads();
  {
    const int cl = (t & 15) * 4, n0 = t >> 4;  // 16 n-rows per pass
    u16* xtp = xT + ((size_t)b * 4096 + nb) * 512 + cb;
#pragma unroll
    for (int p = 0; p < 4; ++p) {
      const int nl = n0 + p * 16;
      ushort4 o;
      o.x = f2bf(tile[cl][nl]);
      o.y = f2bf(tile[cl + 1][nl]);
      o.z = f2bf(tile[cl + 2][nl]);
      o.w = f2bf(tile[cl + 3][nl]);
      *(ushort4*)(xtp + (size_t)nl * 512 + cl) = o;
    }
  }
}

// weights -> bf16. wqk = concat(Wq,Wk) (128x512), wv (512x512)
__global__ __launch_bounds__(256) void k_wcast(const float* __restrict__ Wq,
                                               const float* __restrict__ Wk,
                                               const float* __restrict__ Wv,
                                               u16* __restrict__ wqk,
                                               u16* __restrict__ wv) {
  const int idx = blockIdx.x * 256 + threadIdx.x;
  if (idx < 128 * 512) {
    const int r = idx >> 9, c = idx & 511;
    const float f = (r < 64) ? Wq[r * 512 + c] : Wk[(r - 64) * 512 + c];
    wqk[idx] = f2bf(f);
  } else {
    const int j = idx - 128 * 512;
    if (j < 512 * 512) wv[j] = f2bf(Wv[j]);
  }
}

// ------ bf16 gemm_bt core, R16: 8 waves, dbuf, counted vmcnt, 128x128 -------
__device__ __forceinline__ void gemm8_bt(const u16* __restrict__ A,
                                         const u16* __restrict__ B,
                                         const int K, const int rowA0,
                                         const int colB0, u16* smem,
                                         f32x4 acc[4][2]) {
  const int t = threadIdx.x;
  const int lane = t & 63, w = t >> 6;   // 8 waves
  const int quad = lane >> 4, l15 = lane & 15;
  const int wr = w >> 2, wc = w & 3;     // 2 x 4 wave grid
  const f32x4 zero = {0.f, 0.f, 0.f, 0.f};
#pragma unroll
  for (int i = 0; i < 4; ++i)
#pragma unroll
    for (int j = 0; j < 2; ++j) acc[i][j] = zero;

  const int srow = t >> 3;                  // 0..63
  const int c8 = (lane & 7) ^ (lane >> 3);  // swizzled 16B chunk
  const u16* ga = A + (size_t)(rowA0 + srow) * K + c8 * 8;
  const u16* gb = B + (size_t)(colB0 + srow) * K + c8 * 8;
  const size_t rK64 = (size_t)64 * K;

#define STAGE_G(bi, k0)                                                        \
  do {                                                                         \
    char* Ab = (char*)smem + (bi) * 32768 + w * 1024;                          \
    char* Bb = (char*)smem + (bi) * 32768 + 16384 + w * 1024;                  \
    ASYNC16(ga + (k0), Ab);                                                    \
    ASYNC16(ga + (k0) + rK64, Ab + 8192);                                      \
    ASYNC16(gb + (k0), Bb);                                                    \
    ASYNC16(gb + (k0) + rK64, Bb + 8192);                                      \
  } while (0)

  const int sw0 = (quad) ^ (l15 & 7);
  const int sw1 = (4 + quad) ^ (l15 & 7);

  const int nIt = K >> 6;  // K/64 tiles
  STAGE_G(0, 0);
  STAGE_G(1, 64);

  for (int it = 0; it < nIt; ++it) {
    if (it < nIt - 1)
      __builtin_amdgcn_s_waitcnt(0x0F74);  // vmcnt<=4: tile-it's 4 retired
    else
      __builtin_amdgcn_s_waitcnt(WAIT_VM0);
    asm volatile("" ::: "memory");
    __builtin_amdgcn_s_barrier();
    asm volatile("" ::: "memory");

    const u16* As = smem + (it & 1) * 16384;
    const u16* Bs = As + 8192;
#pragma unroll
    for (int s = 0; s < 2; ++s) {
      const int sw = s ? sw1 : sw0;
      short8 a[4], b[2];
#pragma unroll
      for (int i = 0; i < 4; ++i)
        a[i] = *(const short8*)(As + (wr * 64 + i * 16 + l15) * 64 + sw * 8);
#pragma unroll
      for (int j = 0; j < 2; ++j)
        b[j] = *(const short8*)(Bs + (wc * 32 + j * 16 + l15) * 64 + sw * 8);
      __builtin_amdgcn_s_setprio(1);
#pragma unroll
      for (int i = 0; i < 4; ++i)
#pragma unroll
        for (int j = 0; j < 2; ++j)
          acc[i][j] = __builtin_amdgcn_mfma_f32_16x16x32_bf16(a[i], b[j],
                                                              acc[i][j], 0, 0, 0);
      __builtin_amdgcn_s_setprio(0);
    }
    asm volatile("" ::: "memory");
    __builtin_amdgcn_s_barrier();
    asm volatile("" ::: "memory");
    if (it + 2 < nIt) STAGE_G(it & 1, (it + 2) * 64);
  }
#undef STAGE_G
}

// ---- merged projections: by<4 -> v tile; by==4 -> qk tile (512 thr) --------
__global__ __launch_bounds__(512, 4) void k_proj(const u16* __restrict__ xT,
                                                 const u16* __restrict__ wqk,
                                                 const u16* __restrict__ wv,
                                                 const float* __restrict__ bq,
                                                 const float* __restrict__ bk,
                                                 const float* __restrict__ bv,
                                                 u16* __restrict__ q,
                                                 u16* __restrict__ kT,
                                                 u8* __restrict__ v8) {
  __shared__ u16 smem[32768];  // 64 KB: 2 x (A 16KB | B 16KB)
  const int b = blockIdx.z;
  const int by = blockIdx.y;
  const int t = threadIdx.x, lane = t & 63, w = t >> 6;
  const int quad = lane >> 4, l15 = lane & 15;
  const int wr = w >> 2, wc = w & 3;
  f32x4 acc[4][2];

  if (by == 4) {  // q/k projection: C[n][o2] = xT @ wqk^T
    const int rowA0 = blockIdx.x * 128;
    gemm8_bt(xT + (size_t)b * 4096 * 512, wqk, 512, rowA0, 0, smem, acc);
#pragma unroll
    for (int j = 0; j < 2; ++j) {
      const int col = wc * 32 + j * 16 + l15;
      const float bias = (col < 64) ? bq[col] : bk[col - 64];
#pragma unroll
      for (int i = 0; i < 4; ++i) {
#pragma unroll
        for (int r = 0; r < 4; ++r) {
          const int row = rowA0 + wr * 64 + i * 16 + quad * 4 + r;
          const float val = acc[i][j][r] + bias;
          if (col < 64)
            q[((size_t)b * 4096 + row) * 64 + col] = f2bf(val);
          else
            kT[((size_t)b * 4096 + row) * 64 + (col - 64)] = f2bf(val);
        }
      }
    }
  } else {  // v projection: v8[c][n] = e4m3(Wv @ x + bv)
    const int rowA0 = by * 128;
    const int colB0 = blockIdx.x * 128;
    gemm8_bt(wv, xT + (size_t)b * 4096 * 512, 512, rowA0, colB0, smem, acc);
#pragma unroll
    for (int i = 0; i < 4; ++i) {
#pragma unroll
      for (int r = 0; r < 4; ++r) {
        const int row = rowA0 + wr * 64 + i * 16 + quad * 4 + r;
        const float bias = bv[row];
#pragma unroll
        for (int j = 0; j < 2; ++j) {
          const int col = colB0 + wc * 32 + j * 16 + l15;
          v8[((size_t)b * 512 + row) * 4096 + col] = f2fp8(acc[i][j][r] + bias);
        }
      }
    }
  }
}

// ------------- fused attention+PV, single-barrier pipelined ------------------
// Interval j (j=0..32): [j>0: lgkm0+vmcnt0+barrier; stage v(j) (j<32),
// k(j+1) (j+1<32)]; [j<32: QK(j)+exp(j) -> P_lds[j&1]]; [j>0: PV(j-1) from
// P_lds[(j-1)&1], v_lds[(j-1)&1]]. One barrier/iter; PV overlaps QK/exp.
// Buffer recycle: every reused buffer's last reader finished before the
// preceding barrier (per-wave lgkm0 before barrier arrival).
__global__ __launch_bounds__(1024, 4) void k_fused(
    const u16* __restrict__ q, const u16* __restrict__ kT,
    const u8* __restrict__ v8, const float* __restrict__ x,
    const float* __restrict__ gamma, float* __restrict__ out) {
  __shared__ u16 k_lds[2][128 * 64];    // 32 KB, row-XOR swizzle
  __shared__ u8 v_lds[2][2][256 * 64];  // 64 KB [buf][ks][256 c][64 B]
  __shared__ u8 P_lds[2][2][8192];      // 32 KB [pb][ks][128 n][64 B] bf8
  __shared__ float lsum_lds[8][128];    // 4 KB per-m-strip partials

  const int t = threadIdx.x;
  const int l = t & 63, w = t >> 6;  // 16 waves
  const int quad = l >> 4, l15 = l & 15;
  const int l31 = l & 31, h = l >> 5;

  const int n0 = blockIdx.x * 128;
  const int c0 = blockIdx.y * 256;
  const int b = blockIdx.z;

  const u16* qg = q + ((size_t)b * 4096 + n0) * 64;
  const u16* kg = kT + (size_t)b * 4096 * 64;
  const u8* vg = v8 + ((size_t)b * 512 + c0) * 4096;

  // staging source addrs (LDS dst = wave-uniform base + lane*16)
  const int kr = t >> 3, kc = t & 7;  // k/q: 1024 chunks, 128B rows
  const u16* qsg = qg + kr * 64 + (kc ^ (kr & 7)) * 8;
  const u16* ksg = kg + kr * 64 + (kc ^ (kr & 7)) * 8;  // + m0*64
  const int vr = t >> 2, va = t & 3;  // v: 1024 chunks/ks, 64B rows
  const u8* vsg = vg + (size_t)vr * 4096 + (va ^ ((vr >> 1) & 3)) * 16;

#define STAGE_K(bi, m0)                                                        \
  ASYNC16(ksg + (size_t)(m0) * 64, (char*)k_lds[bi] + w * 1024)
#define STAGE_V(bi, m0)                                                        \
  do {                                                                         \
    ASYNC16(vsg + (m0), (char*)v_lds[bi][0] + w * 1024);                       \
    ASYNC16(vsg + (m0) + 64, (char*)v_lds[bi][1] + w * 1024);                  \
  } while (0)

  // ---- prologue: q into P area; k(0), v(0), k(1) ----
  ASYNC16(qsg, (char*)&P_lds[0][0][0] + w * 1024);
  STAGE_K(0, 0);
  STAGE_V(0, 0);
  STAGE_K(1, 128);
  __builtin_amdgcn_s_waitcnt(WAIT_VM4);  // q (oldest) landed
  __builtin_amdgcn_s_barrier();
  asm volatile("" ::: "memory");
  const int ms = w >> 1, nh = w & 1;  // QK decomposition
  const int sw0 = quad ^ (l15 & 7);
  const int sw1 = (4 + quad) ^ (l15 & 7);
  short8 af[4][2];  // loop-invariant q fragments (strip s, sweep e)
#pragma unroll
  for (int s = 0; s < 4; ++s) {
    const u16* qrow = (const u16*)&P_lds[0][0][0] + (nh * 64 + s * 16 + l15) * 64;
    af[s][0] = *(const short8*)(qrow + sw0 * 8);
    af[s][1] = *(const short8*)(qrow + sw1 * 8);
  }
  asm volatile("" ::: "memory");
  __builtin_amdgcn_s_waitcnt(WAIT_LGKM0);  // q reads done -> P writable
  __builtin_amdgcn_s_waitcnt(WAIT_VM0);    // k(0), v(0), k(1) in LDS
  __builtin_amdgcn_s_barrier();
  asm volatile("" ::: "memory");

  // PV decomposition (k_pv layout), wave grid 4x4
  const int wrp = w >> 2, wcp = w & 3;
  int rowA[2], sA1[2], sA2[2];
#pragma unroll
  for (int i = 0; i < 2; ++i) {
    rowA[i] = wrp * 64 + i * 32 + l31;
    const int fa = (rowA[i] >> 1) & 3;
    sA1[i] = (2 * h) ^ fa;
    sA2[i] = (2 * h + 1) ^ fa;
  }
  const int rowB = wcp * 32 + l31;
  const int fbB = (rowB >> 1) & 3;
  const int sB1 = (2 * h) ^ fbB;
  const int sB2 = (2 * h + 1) ^ fbB;

  // P write base (pb=0): ks = ms>>2, n-row nh*64+s*16+l15, chunk (ms&3)^fbW
  const int fbW = (l15 >> 1) & 3;
  u8* Pwbase = &P_lds[0][ms >> 2][0] + (nh * 64 + l15) * 64 +
               (((ms & 3) ^ fbW) * 16) + quad * 4;

  const int krow_off = (ms * 16 + l15) * 64;  // k read row offset (u16)

  f32x16 acc[2];
#pragma unroll
  for (int i = 0; i < 2; ++i)
#pragma unroll
    for (int r = 0; r < 16; ++r) acc[i][r] = 0.f;

  float lsums[4] = {0.f, 0.f, 0.f, 0.f};
  const f32x4 zero = {0.f, 0.f, 0.f, 0.f};

  for (int j = 0; j <= 32; ++j) {
    if (j > 0) {
      __builtin_amdgcn_s_waitcnt(WAIT_LGKM0);  // own P(j-1) writes done
      __builtin_amdgcn_s_waitcnt(WAIT_VM0);    // v(j-1), k(j) in LDS
      asm volatile("" ::: "memory");
      __builtin_amdgcn_s_barrier();            // P(j-1)/k(j)/v(j-1) visible;
                                               // reused buffers reader-free
      asm volatile("" ::: "memory");
      if (j < 32) STAGE_V(j & 1, j * 128);
      if (j + 1 < 32) STAGE_K((j + 1) & 1, (j + 1) * 128);
    }

    if (j < 32) {
      // ---- QK(j): k read once, q from regs ----
      const u16* kb = k_lds[j & 1];
      const short8 kf0 = *(const short8*)(kb + krow_off + sw0 * 8);
      const short8 kf1 = *(const short8*)(kb + krow_off + sw1 * 8);
      f32x4 eacc[4];
#pragma unroll
      for (int s = 0; s < 4; ++s) eacc[s] = zero;
      __builtin_amdgcn_s_setprio(1);
#pragma unroll
      for (int s = 0; s < 4; ++s)
        eacc[s] = __builtin_amdgcn_mfma_f32_16x16x32_bf16(kf0, af[s][0],
                                                          eacc[s], 0, 0, 0);
#pragma unroll
      for (int s = 0; s < 4; ++s)
        eacc[s] = __builtin_amdgcn_mfma_f32_16x16x32_bf16(kf1, af[s][1],
                                                          eacc[s], 0, 0, 0);
      __builtin_amdgcn_s_setprio(0);

      // ---- exp(j) -> bf8 -> P_lds[j&1] ----
      u8* Pw = Pwbase + (j & 1) * 16384;
#pragma unroll
      for (int s = 0; s < 4; ++s) {
        const float e0 = fminf(__expf(eacc[s][0] - EXP_SHIFT), EXP_CAP);
        const float e1 = fminf(__expf(eacc[s][1] - EXP_SHIFT), EXP_CAP);
        const float e2 = fminf(__expf(eacc[s][2] - EXP_SHIFT), EXP_CAP);
        const float e3 = fminf(__expf(eacc[s][3] - EXP_SHIFT), EXP_CAP);
        lsums[s] += (e0 + e1) + (e2 + e3);
        int pk = __builtin_amdgcn_cvt_pk_bf8_f32(e0, e1, 0, false);
        pk = __builtin_amdgcn_cvt_pk_bf8_f32(e2, e3, pk, true);
        *(int*)(Pw + s * 1024) = pk;  // row step 16 rows * 64B
      }
    }

    if (j > 0) {
      // ---- PV(j-1): acc += v(e4m3) @ P^T(bf8), independent of QK/exp(j) ----
      const int pc = (j - 1) & 1;
#pragma unroll
      for (int ks = 0; ks < 2; ++ks) {
        const u8* Vb = v_lds[pc][ks];
        const u8* Pb = &P_lds[pc][ks][0];
        i32x8 bb;
        {
          const u8* pb = Pb + rowB * 64;
          const i32x4 blo = *(const i32x4*)(pb + sB1 * 16);
          const i32x4 bhi = *(const i32x4*)(pb + sB2 * 16);
          bb[0] = blo[0]; bb[1] = blo[1]; bb[2] = blo[2]; bb[3] = blo[3];
          bb[4] = bhi[0]; bb[5] = bhi[1]; bb[6] = bhi[2]; bb[7] = bhi[3];
        }
        __builtin_amdgcn_s_setprio(1);
#pragma unroll
        for (int i = 0; i < 2; ++i) {
          const u8* pa = Vb + rowA[i] * 64;
          const i32x4 lo = *(const i32x4*)(pa + sA1[i] * 16);
          const i32x4 hi = *(const i32x4*)(pa + sA2[i] * 16);
          i32x8 a;
          a[0] = lo[0]; a[1] = lo[1]; a[2] = lo[2]; a[3] = lo[3];
          a[4] = hi[0]; a[5] = hi[1]; a[6] = hi[2]; a[7] = hi[3];
          acc[i] = __builtin_amdgcn_mfma_scale_f32_32x32x64_f8f6f4(
              a, bb, acc[i], 0 /*A=e4m3*/, 1 /*B=bf8*/, 0, 0x7F, 0, 0x7F);
        }
        __builtin_amdgcn_s_setprio(0);
      }
    }
  }
#undef STAGE_K
#undef STAGE_V

  // ---- lsum reduce: quad-sum per (strip, l15), store per m-strip ----
#pragma unroll
  for (int s = 0; s < 4; ++s) {
    lsums[s] += __shfl_xor(lsums[s], 16);
    lsums[s] += __shfl_xor(lsums[s], 32);
  }
  if (l < 16) {
#pragma unroll
    for (int s = 0; s < 4; ++s)
      lsum_lds[ms][nh * 64 + s * 16 + l] = lsums[s];
  }
  asm volatile("" ::: "memory");
  __builtin_amdgcn_s_waitcnt(WAIT_LGKM0);
  __builtin_amdgcn_s_barrier();
  asm volatile("" ::: "memory");

  // ---- epilogue: out = gamma/lsum[n] * acc + x ----
  const float g = gamma[0];
  const int col = n0 + wcp * 32 + l31;
  const int nc = wcp * 32 + l31;
  float den = 0.f;
#pragma unroll
  for (int m = 0; m < 8; ++m) den += lsum_lds[m][nc];
  const float gil = g / den;
#pragma unroll
  for (int i = 0; i < 2; ++i) {
#pragma unroll
    for (int r = 0; r < 16; ++r) {
      const int rloc = (r & 3) + 8 * (r >> 2) + 4 * h;
      const int row = c0 + wrp * 64 + i * 32 + rloc;
      const size_t idx = ((size_t)b * 512 + row) * 4096 + col;
      out[idx] = gil * acc[i][r] + x[idx];
    }
  }
}

extern "C" void kernel_launch(void* const* d_in, const int* in_sizes, int n_in,
                              void* d_out, int out_size, void* d_ws,
                              size_t ws_size, hipStream_t stream) {
  const float* x = (const float*)d_in[0];
  const float* Wq = (const float*)d_in[1];
  const float* bq = (const float*)d_in[2];
  const float* Wk = (const float*)d_in[3];
  const float* bk = (const float*)d_in[4];
  const float* Wv = (const float*)d_in[5];
  const float* bv = (const float*)d_in[6];
  const float* gamma = (const float*)d_in[7];
  float* out = (float*)d_out;

  char* ws = (char*)d_ws;
  u16* xT = (u16*)(ws);                    // 16,777,216 B : (B,N,C) bf16
  u16* wqk = (u16*)(ws + 16777216);        //    131,072 B
  u16* wv = (u16*)(ws + 16908288);         //    524,288 B
  u16* qb = (u16*)(ws + 17432576);         //  2,097,152 B : (B,N,64)
  u16* ktb = (u16*)(ws + 19529728);        //  2,097,152 B : (B,N,64)
  u8* v8 = (u8*)(ws + 21626880);           //  8,388,608 B : (B,C,N) e4m3
  // total ws use: 30,015,488 B

  k_transpose<<<dim3(64, 8, 4), 256, 0, stream>>>(x, xT);
  k_wcast<<<dim3(1280), 256, 0, stream>>>(Wq, Wk, Wv, wqk, wv);
  k_proj<<<dim3(32, 5, 4), 512, 0, stream>>>(xT, wqk, wv, bq, bk, bv,
                                             qb, ktb, v8);
  k_fused<<<dim3(32, 2, 4), 1024, 0, stream>>>(qb, ktb, v8, x, gamma, out);
}